// Round 3
// baseline (925.729 us; speedup 1.0000x reference)
//
#include <hip/hip_runtime.h>

#define NN 100000
#define HH 512
#define GG 512
#define NPACK 1280

typedef unsigned short u16;
typedef __bf16 bf16x8 __attribute__((ext_vector_type(8)));
typedef unsigned short u16x8 __attribute__((ext_vector_type(8)));
typedef float f32x4 __attribute__((ext_vector_type(4)));

__device__ __forceinline__ u16 f2bf(float f) {
    unsigned u = __float_as_uint(f);
    unsigned r = u + 0x7FFFu + ((u >> 16) & 1u);   // RNE
    return (u16)(r >> 16);
}
__device__ __forceinline__ float bf2f(u16 b) {
    return __uint_as_float(((unsigned)b) << 16);
}

// ---------------- prep: packed W^T bf16 + bias + wvec + zero out_emb + segment bounds ----
// packed col n: [0,256) = ga_g_w1 ; [256,768) = ga_n_w ; [768,1280) = g_w1
__global__ void k_prep(const float* __restrict__ gw1, const float* __restrict__ gb1,
                       const float* __restrict__ gw2v,
                       const float* __restrict__ nw, const float* __restrict__ nb,
                       const float* __restrict__ aw1, const float* __restrict__ ab1,
                       const float* __restrict__ aw2, const int* __restrict__ batch,
                       u16* __restrict__ WT, float* __restrict__ bias, float* __restrict__ wvec,
                       float* __restrict__ out_emb, int* __restrict__ starts) {
    int idx = blockIdx.x * blockDim.x + threadIdx.x;
    int stride = gridDim.x * blockDim.x;
    for (int i = idx; i < NPACK * 512; i += stride) {
        int n = i >> 9, k = i & 511;
        float v;
        if (n < 256)      v = gw1[k * 256 + n];
        else if (n < 768) v = nw[k * 512 + (n - 256)];
        else              v = aw1[k * 512 + (n - 768)];
        WT[n * 512 + k] = f2bf(v);   // row n contiguous in k
    }
    for (int n = idx; n < NPACK; n += stride) {
        float bi, wv;
        if (n < 256)      { bi = gb1[n];       wv = gw2v[n]; }
        else if (n < 768) { bi = nb[n - 256];  wv = 0.f; }
        else {
            bi = ab1[n - 768];
            float s = 0.f;
            for (int h = 0; h < 8; ++h) s += aw2[(n - 768) * 8 + h];
            wv = s * 0.125f;
        }
        bias[n] = bi; wvec[n] = wv;
    }
    for (int i = idx; i < GG * HH; i += stride) out_emb[i] = 0.f;
    for (int g = idx; g <= GG; g += stride) {
        if (g == GG) { starts[GG] = NN; continue; }
        int lo = 0, hi = NN;
        while (lo < hi) { int mid = (lo + hi) >> 1; if (batch[mid] < g) lo = mid + 1; else hi = mid; }
        starts[g] = lo;
    }
}

// ---------------- fused GEMM: A (32 rows/wave) in registers, B global->VGPR, NO LDS ----
// block = 128 rows x 1280 packed cols (20 strips of 64). 4 waves stacked on m.
// No barrier in the K loop: B-frag loads pipeline under fine-grained vmcnt.
// nt 0-3: gate score | nt 4-11: xt store | nt 12-19: att score. Scores in regs.
__global__ __launch_bounds__(256, 2)
void k_gemm(const float* __restrict__ X, const u16* __restrict__ B,
            const float* __restrict__ bias, const float* __restrict__ wvec,
            const float* __restrict__ gb2, const float* __restrict__ ab2,
            u16* __restrict__ xt, float* __restrict__ gs, float* __restrict__ as_) {
    const int tid = threadIdx.x;
    const int lane = tid & 63;
    const int w = tid >> 6;                 // wave -> rows [w*32, w*32+32)
    const int m0 = blockIdx.x * 128;
    const int r16 = lane & 15, kq = lane >> 4;

    float b2 = gb2[0];
    float bb = 0.f;
#pragma unroll
    for (int h = 0; h < 8; ++h) bb += ab2[h];
    bb *= 0.125f;

    // ---- A panel: global fp32 -> convert -> registers (read once) ----
    bf16x8 a_reg[2][16];                    // 2 m-subs x 16 k-steps
#pragma unroll
    for (int i = 0; i < 2; ++i) {
        int row = m0 + w * 32 + i * 16 + r16;
        if (row >= NN) row = NN - 1;
        const float* xp = X + (size_t)row * 512 + kq * 8;
#pragma unroll
        for (int kt = 0; kt < 16; ++kt) {
            float4 f0 = *(const float4*)(xp + kt * 32);
            float4 f1 = *(const float4*)(xp + kt * 32 + 4);
            u16x8 u;
            u[0] = f2bf(f0.x); u[1] = f2bf(f0.y); u[2] = f2bf(f0.z); u[3] = f2bf(f0.w);
            u[4] = f2bf(f1.x); u[5] = f2bf(f1.y); u[6] = f2bf(f1.z); u[7] = f2bf(f1.w);
            a_reg[i][kt] = __builtin_bit_cast(bf16x8, u);
        }
    }

    float sg[2][4], sa[2][4];
#pragma unroll
    for (int i = 0; i < 2; ++i)
#pragma unroll
        for (int r = 0; r < 4; ++r) { sg[i][r] = 0.f; sa[i][r] = 0.f; }

    const int quad = lane >> 4, l16 = lane & 15;
    // B-frag lane base: lane holds B[n = n0 + j*16 + l16][k = kq*8 .. +8)
    const u16* Bp = B + (size_t)r16 * 512 + kq * 8;

    for (int nt = 0; nt < 20; ++nt) {
        f32x4 acc[2][4];
#pragma unroll
        for (int i = 0; i < 2; ++i)
#pragma unroll
            for (int j = 0; j < 4; ++j) acc[i][j] = {0.f, 0.f, 0.f, 0.f};

        const u16* Bn = Bp + (size_t)nt * 64 * 512;
#pragma unroll
        for (int kt = 0; kt < 16; ++kt) {
            bf16x8 b[4];
#pragma unroll
            for (int j = 0; j < 4; ++j)
                b[j] = *(const bf16x8*)(Bn + (size_t)j * 16 * 512 + kt * 32);
#pragma unroll
            for (int i = 0; i < 2; ++i)
#pragma unroll
                for (int j = 0; j < 4; ++j)
                    acc[i][j] = __builtin_amdgcn_mfma_f32_16x16x32_bf16(
                        a_reg[i][kt], b[j], acc[i][j], 0, 0, 0);
        }

        // ---- per-strip epilogue. C/D: col = lane&15, row = quad*4 + reg [m89] ----
        const int n0 = nt * 64;
        if (nt >= 4 && nt < 12) {
#pragma unroll
            for (int i = 0; i < 2; ++i) {
#pragma unroll
                for (int r = 0; r < 4; ++r) {
                    int rg = m0 + w * 32 + i * 16 + quad * 4 + r;
                    if (rg < NN) {
#pragma unroll
                        for (int j = 0; j < 4; ++j) {
                            int colg = n0 + j * 16 + l16;
                            float v = acc[i][j][r] + bias[colg];
                            v = fmaxf(v, 0.f);
                            xt[(size_t)rg * 512 + (colg - 256)] = f2bf(v);
                        }
                    }
                }
            }
        } else if (nt < 4) {
#pragma unroll
            for (int i = 0; i < 2; ++i)
#pragma unroll
                for (int r = 0; r < 4; ++r) {
                    float p = 0.f;
#pragma unroll
                    for (int j = 0; j < 4; ++j) {
                        int colg = n0 + j * 16 + l16;
                        float v = acc[i][j][r] + bias[colg];
                        v = fmaxf(v, 0.f);
                        p += v * wvec[colg];
                    }
                    sg[i][r] += p;
                }
        } else {
#pragma unroll
            for (int i = 0; i < 2; ++i)
#pragma unroll
                for (int r = 0; r < 4; ++r) {
                    float p = 0.f;
#pragma unroll
                    for (int j = 0; j < 4; ++j) {
                        int colg = n0 + j * 16 + l16;
                        float v = acc[i][j][r] + bias[colg];
                        v = fmaxf(v, 0.f);
                        p += v * wvec[colg];
                    }
                    sa[i][r] += p;
                }
        }
        __syncthreads();   // bound wave drift -> keep B-frag L1 temporal reuse across waves
    }

    // ---- final scores: reduce over the 16 col-lanes, one coalesced write ----
#pragma unroll
    for (int i = 0; i < 2; ++i)
#pragma unroll
        for (int r = 0; r < 4; ++r) {
            float pg = sg[i][r], pa = sa[i][r];
            pg += __shfl_xor(pg, 1); pg += __shfl_xor(pg, 2);
            pg += __shfl_xor(pg, 4); pg += __shfl_xor(pg, 8);
            pa += __shfl_xor(pa, 1); pa += __shfl_xor(pa, 2);
            pa += __shfl_xor(pa, 4); pa += __shfl_xor(pa, 8);
            int rg = m0 + w * 32 + i * 16 + quad * 4 + r;
            if (l16 == 0 && rg < NN) {
                gs[rg] = pg + b2;
                as_[rg] = pa + bb;
            }
        }
}

// ------- per-graph softmax: max + denom + normalize, one block per graph -------
__global__ void k_seg(const float* __restrict__ gs, const float* __restrict__ as_,
                      const int* __restrict__ starts,
                      float* __restrict__ gate, float* __restrict__ attn) {
    int g = blockIdx.x;
    int s0 = starts[g], s1 = starts[g + 1];
    int tid = threadIdx.x, lane = tid & 63, w = tid >> 6;
    __shared__ float red[8];
    float lmg = -3.0e38f, lma = -3.0e38f;
    for (int i = s0 + tid; i < s1; i += 256) {
        lmg = fmaxf(lmg, gs[i]); lma = fmaxf(lma, as_[i]);
    }
    for (int o = 32; o; o >>= 1) {
        lmg = fmaxf(lmg, __shfl_xor(lmg, o));
        lma = fmaxf(lma, __shfl_xor(lma, o));
    }
    if (lane == 0) { red[w] = lmg; red[4 + w] = lma; }
    __syncthreads();
    float Mg = fmaxf(fmaxf(red[0], red[1]), fmaxf(red[2], red[3]));
    float Ma = fmaxf(fmaxf(red[4], red[5]), fmaxf(red[6], red[7]));
    __syncthreads();
    float sgv = 0.f, sav = 0.f;
    for (int i = s0 + tid; i < s1; i += 256) {
        sgv += expf(gs[i] - Mg); sav += expf(as_[i] - Ma);
    }
    for (int o = 32; o; o >>= 1) { sgv += __shfl_xor(sgv, o); sav += __shfl_xor(sav, o); }
    if (lane == 0) { red[w] = sgv; red[4 + w] = sav; }
    __syncthreads();
    float invg = 1.f / (red[0] + red[1] + red[2] + red[3] + 1e-16f);
    float inva = 1.f / (red[4] + red[5] + red[6] + red[7] + 1e-16f);
    for (int i = s0 + tid; i < s1; i += 256) {
        gate[i] = expf(gs[i] - Mg) * invg;
        attn[i] = expf(as_[i] - Ma) * inva;
    }
}

// ---------------- graph embedding: segment-weighted sum of xt ----------------
__global__ void k_emb(const u16* __restrict__ xt, const float* __restrict__ gate,
                      const int* __restrict__ starts, float* __restrict__ out) {
    int g = blockIdx.y;
    int part = blockIdx.x;
    int s0 = starts[g], s1 = starts[g + 1];
    int len = s1 - s0;
    int p0 = s0 + (len * part) / 4, p1 = s0 + (len * (part + 1)) / 4;
    int c2 = threadIdx.x;
    float a0 = 0.f, a1 = 0.f;
    for (int n = p0; n < p1; ++n) {
        float gn = gate[n];
        ushort2 u = reinterpret_cast<const ushort2*>(xt + (size_t)n * 512)[c2];
        a0 += gn * bf2f(u.x);
        a1 += gn * bf2f(u.y);
    }
    atomicAdd(&out[g * 512 + 2 * c2], a0);
    atomicAdd(&out[g * 512 + 2 * c2 + 1], a1);
}

extern "C" void kernel_launch(void* const* d_in, const int* in_sizes, int n_in,
                              void* d_out, int out_size, void* d_ws, size_t ws_size,
                              hipStream_t stream) {
    const float* x       = (const float*)d_in[0];
    const int*   batch   = (const int*)d_in[1];
    const float* ga_g_w1 = (const float*)d_in[2];
    const float* ga_g_b1 = (const float*)d_in[3];
    const float* ga_g_w2 = (const float*)d_in[4];
    const float* ga_g_b2 = (const float*)d_in[5];
    const float* ga_n_w  = (const float*)d_in[6];
    const float* ga_n_b  = (const float*)d_in[7];
    const float* g_w1    = (const float*)d_in[8];
    const float* g_b1    = (const float*)d_in[9];
    const float* g_w2    = (const float*)d_in[10];
    const float* g_b2    = (const float*)d_in[11];

    float* out_emb = (float*)d_out;                  // (512, 512)
    float* out_att = out_emb + GG * HH;              // (100000,)

    char* p = (char*)d_ws;
    size_t off = 0;
    auto alloc = [&](size_t bytes) -> char* {
        char* q = p + off;
        off += (bytes + 255) & ~(size_t)255;
        return q;
    };
    u16*   xt    = (u16*)  alloc((size_t)NN * HH * 2);      // relu(x@ga_n_w+b) bf16
    u16*   WT    = (u16*)  alloc((size_t)NPACK * 512 * 2);  // packed W^T bf16
    float* bias  = (float*)alloc(NPACK * 4);
    float* wvec  = (float*)alloc(NPACK * 4);
    float* gs    = (float*)alloc((size_t)NN * 4);
    float* as_   = (float*)alloc((size_t)NN * 4);
    float* gate  = (float*)alloc((size_t)NN * 4);
    int*   starts= (int*)  alloc((GG + 1) * 4);

    k_prep<<<2560, 256, 0, stream>>>(ga_g_w1, ga_g_b1, ga_g_w2, ga_n_w, ga_n_b,
                                     g_w1, g_b1, g_w2, batch, WT, bias, wvec, out_emb, starts);
    k_gemm<<<782, 256, 0, stream>>>(x, WT, bias, wvec, ga_g_b2, g_b2, xt, gs, as_);
    k_seg<<<GG, 256, 0, stream>>>(gs, as_, starts, gate, out_att);
    k_emb<<<dim3(4, GG), 256, 0, stream>>>(xt, gate, starts, out_emb);
}

// Round 4
// 814.000 us; speedup vs baseline: 1.1373x; 1.1373x over previous
//
#include <hip/hip_runtime.h>

#define NN 100000
#define HH 512
#define GG 512
#define NPACK 1280

typedef unsigned short u16;
typedef __bf16 bf16x8 __attribute__((ext_vector_type(8)));
typedef unsigned short u16x8 __attribute__((ext_vector_type(8)));
typedef float f32x16 __attribute__((ext_vector_type(16)));

__device__ __forceinline__ u16 f2bf(float f) {
    unsigned u = __float_as_uint(f);
    unsigned r = u + 0x7FFFu + ((u >> 16) & 1u);   // RNE
    return (u16)(r >> 16);
}
__device__ __forceinline__ float bf2f(u16 b) {
    return __uint_as_float(((unsigned)b) << 16);
}

// ---------------- prep: packed W^T bf16 + bias + wvec + zero out_emb + segment bounds ----
// packed col n: [0,256) = ga_g_w1 ; [256,768) = ga_n_w ; [768,1280) = g_w1
__global__ void k_prep(const float* __restrict__ gw1, const float* __restrict__ gb1,
                       const float* __restrict__ gw2v,
                       const float* __restrict__ nw, const float* __restrict__ nb,
                       const float* __restrict__ aw1, const float* __restrict__ ab1,
                       const float* __restrict__ aw2, const int* __restrict__ batch,
                       u16* __restrict__ WT, float* __restrict__ bias, float* __restrict__ wvec,
                       float* __restrict__ out_emb, int* __restrict__ starts) {
    int idx = blockIdx.x * blockDim.x + threadIdx.x;
    int stride = gridDim.x * blockDim.x;
    for (int i = idx; i < NPACK * 512; i += stride) {
        int n = i >> 9, k = i & 511;
        float v;
        if (n < 256)      v = gw1[k * 256 + n];
        else if (n < 768) v = nw[k * 512 + (n - 256)];
        else              v = aw1[k * 512 + (n - 768)];
        WT[n * 512 + k] = f2bf(v);   // row n contiguous in k
    }
    for (int n = idx; n < NPACK; n += stride) {
        float bi, wv;
        if (n < 256)      { bi = gb1[n];       wv = gw2v[n]; }
        else if (n < 768) { bi = nb[n - 256];  wv = 0.f; }
        else {
            bi = ab1[n - 768];
            float s = 0.f;
            for (int h = 0; h < 8; ++h) s += aw2[(n - 768) * 8 + h];
            wv = s * 0.125f;
        }
        bias[n] = bi; wvec[n] = wv;
    }
    for (int i = idx; i < GG * HH; i += stride) out_emb[i] = 0.f;
    for (int g = idx; g <= GG; g += stride) {
        if (g == GG) { starts[GG] = NN; continue; }
        int lo = 0, hi = NN;
        while (lo < hi) { int mid = (lo + hi) >> 1; if (batch[mid] < g) lo = mid + 1; else hi = mid; }
        starts[g] = lo;
    }
}

// ---- fused GEMM: A (64 rows) in LDS staged once, B global->VGPR, 32x32x16 MFMA ----
// block = 64 rows; wave w computes full 64 rows x strips {w, w+4, w+8, w+12, w+16} (64 cols each).
// Zero barriers in the K loop. nt 0-3: gate | 4-11: xt | 12-19: att.
// LDS A layout: chunk(kt 0..31, rg 0..1): base = kt*2048 + rg*1024; entry lane*16 holds
//   A[row = rg*32 + (lane&31)][k = kt*16 + (lane>>5)*8 .. +8) as bf16x8  -> ds_read_b128 seq.
__global__ __launch_bounds__(256, 2)
void k_gemm(const float* __restrict__ X, const u16* __restrict__ B,
            const float* __restrict__ bias, const float* __restrict__ wvec,
            const float* __restrict__ gb2, const float* __restrict__ ab2,
            u16* __restrict__ xt, float* __restrict__ gs, float* __restrict__ as_) {
    __shared__ __align__(16) char ldsA[65536];
    __shared__ float s_gate[64];
    __shared__ float s_att[64];

    const int tid = threadIdx.x;
    const int lane = tid & 63;
    const int w = tid >> 6;
    const int m0 = blockIdx.x * 64;

    float b2 = gb2[0];
    float bb = 0.f;
#pragma unroll
    for (int h = 0; h < 8; ++h) bb += ab2[h];
    bb *= 0.125f;

    if (tid < 64) { s_gate[tid] = 0.f; s_att[tid] = 0.f; }

    // ---- stage A: global fp32 -> bf16 -> LDS, once ----
    {
        const int r32 = tid & 31, kh = (tid >> 5) & 1, rg = (tid >> 6) & 1;
        const int ks = (tid >> 7) * 16;              // kt range split
        int row = m0 + rg * 32 + r32; if (row >= NN) row = NN - 1;
        const float* xp = X + (size_t)row * 512 + kh * 8;
        char* lw = ldsA + rg * 1024 + (kh * 32 + r32) * 16;
#pragma unroll
        for (int ki = 0; ki < 16; ++ki) {
            int kt = ks + ki;
            float4 f0 = *(const float4*)(xp + kt * 16);
            float4 f1 = *(const float4*)(xp + kt * 16 + 4);
            u16x8 u;
            u[0] = f2bf(f0.x); u[1] = f2bf(f0.y); u[2] = f2bf(f0.z); u[3] = f2bf(f0.w);
            u[4] = f2bf(f1.x); u[5] = f2bf(f1.y); u[6] = f2bf(f1.z); u[7] = f2bf(f1.w);
            *(u16x8*)(lw + kt * 2048) = u;
        }
    }
    __syncthreads();   // the only barrier before the final writeback

    const int r32l = lane & 31, khl = lane >> 5;

    for (int t = 0; t < 5; ++t) {
        const int nt = w + 4 * t;
        const int n0 = nt * 64;
        f32x16 acc00 = {0}, acc01 = {0}, acc10 = {0}, acc11 = {0};

        const u16* b0p = B + (size_t)(n0 + r32l) * 512 + khl * 8;
        const u16* b1p = b0p + 32 * 512;
#pragma unroll
        for (int kt = 0; kt < 32; ++kt) {
            bf16x8 a0 = *(const bf16x8*)(ldsA + kt * 2048 + lane * 16);
            bf16x8 a1 = *(const bf16x8*)(ldsA + kt * 2048 + 1024 + lane * 16);
            bf16x8 b0 = *(const bf16x8*)(b0p + kt * 16);
            bf16x8 b1 = *(const bf16x8*)(b1p + kt * 16);
            acc00 = __builtin_amdgcn_mfma_f32_32x32x16_bf16(a0, b0, acc00, 0, 0, 0);
            acc01 = __builtin_amdgcn_mfma_f32_32x32x16_bf16(a0, b1, acc01, 0, 0, 0);
            acc10 = __builtin_amdgcn_mfma_f32_32x32x16_bf16(a1, b0, acc10, 0, 0, 0);
            acc11 = __builtin_amdgcn_mfma_f32_32x32x16_bf16(a1, b1, acc11, 0, 0, 0);
        }

        // C/D 32x32: col = lane&31, row = (reg&3) + 8*(reg>>2) + 4*(lane>>5)  [m74/m101]
        const int colA = n0 + r32l, colB = colA + 32;
        const float biasA = bias[colA], biasB = bias[colB];
        if (nt >= 4 && nt < 12) {
#pragma unroll
            for (int rg = 0; rg < 2; ++rg) {
                const f32x16 aA = rg ? acc10 : acc00;
                const f32x16 aB = rg ? acc11 : acc01;
#pragma unroll
                for (int reg = 0; reg < 16; ++reg) {
                    int row = m0 + rg * 32 + (reg & 3) + 8 * (reg >> 2) + 4 * khl;
                    if (row < NN) {
                        float v0 = fmaxf(aA[reg] + biasA, 0.f);
                        float v1 = fmaxf(aB[reg] + biasB, 0.f);
                        xt[(size_t)row * 512 + (colA - 256)] = f2bf(v0);
                        xt[(size_t)row * 512 + (colB - 256)] = f2bf(v1);
                    }
                }
            }
        } else {
            float* s_sc = (nt < 4) ? s_gate : s_att;
            const float wvA = wvec[colA], wvB = wvec[colB];
#pragma unroll
            for (int rg = 0; rg < 2; ++rg) {
                const f32x16 aA = rg ? acc10 : acc00;
                const f32x16 aB = rg ? acc11 : acc01;
#pragma unroll
                for (int reg = 0; reg < 16; ++reg) {
                    float v0 = fmaxf(aA[reg] + biasA, 0.f);
                    float v1 = fmaxf(aB[reg] + biasB, 0.f);
                    float p = v0 * wvA + v1 * wvB;
                    p += __shfl_xor(p, 1); p += __shfl_xor(p, 2);
                    p += __shfl_xor(p, 4); p += __shfl_xor(p, 8); p += __shfl_xor(p, 16);
                    if (r32l == 0) {
                        int rl = rg * 32 + (reg & 3) + 8 * (reg >> 2) + 4 * khl;
                        if (m0 + rl < NN) atomicAdd(&s_sc[rl], p);
                    }
                }
            }
        }
    }

    __syncthreads();
    if (tid < 64 && m0 + tid < NN) {
        gs[m0 + tid] = s_gate[tid] + b2;
        as_[m0 + tid] = s_att[tid] + bb;
    }
}

// ------- per-graph softmax: max + denom + normalize, one block per graph -------
__global__ void k_seg(const float* __restrict__ gs, const float* __restrict__ as_,
                      const int* __restrict__ starts,
                      float* __restrict__ gate, float* __restrict__ attn) {
    int g = blockIdx.x;
    int s0 = starts[g], s1 = starts[g + 1];
    int tid = threadIdx.x, lane = tid & 63, w = tid >> 6;
    __shared__ float red[8];
    float lmg = -3.0e38f, lma = -3.0e38f;
    for (int i = s0 + tid; i < s1; i += 256) {
        lmg = fmaxf(lmg, gs[i]); lma = fmaxf(lma, as_[i]);
    }
    for (int o = 32; o; o >>= 1) {
        lmg = fmaxf(lmg, __shfl_xor(lmg, o));
        lma = fmaxf(lma, __shfl_xor(lma, o));
    }
    if (lane == 0) { red[w] = lmg; red[4 + w] = lma; }
    __syncthreads();
    float Mg = fmaxf(fmaxf(red[0], red[1]), fmaxf(red[2], red[3]));
    float Ma = fmaxf(fmaxf(red[4], red[5]), fmaxf(red[6], red[7]));
    __syncthreads();
    float sgv = 0.f, sav = 0.f;
    for (int i = s0 + tid; i < s1; i += 256) {
        sgv += expf(gs[i] - Mg); sav += expf(as_[i] - Ma);
    }
    for (int o = 32; o; o >>= 1) { sgv += __shfl_xor(sgv, o); sav += __shfl_xor(sav, o); }
    if (lane == 0) { red[w] = sgv; red[4 + w] = sav; }
    __syncthreads();
    float invg = 1.f / (red[0] + red[1] + red[2] + red[3] + 1e-16f);
    float inva = 1.f / (red[4] + red[5] + red[6] + red[7] + 1e-16f);
    for (int i = s0 + tid; i < s1; i += 256) {
        gate[i] = expf(gs[i] - Mg) * invg;
        attn[i] = expf(as_[i] - Ma) * inva;
    }
}

// ---------------- graph embedding: segment-weighted sum of xt ----------------
__global__ void k_emb(const u16* __restrict__ xt, const float* __restrict__ gate,
                      const int* __restrict__ starts, float* __restrict__ out) {
    int g = blockIdx.y;
    int part = blockIdx.x;
    int s0 = starts[g], s1 = starts[g + 1];
    int len = s1 - s0;
    int p0 = s0 + (len * part) / 4, p1 = s0 + (len * (part + 1)) / 4;
    int c2 = threadIdx.x;
    float a0 = 0.f, a1 = 0.f;
    for (int n = p0; n < p1; ++n) {
        float gn = gate[n];
        ushort2 u = reinterpret_cast<const ushort2*>(xt + (size_t)n * 512)[c2];
        a0 += gn * bf2f(u.x);
        a1 += gn * bf2f(u.y);
    }
    atomicAdd(&out[g * 512 + 2 * c2], a0);
    atomicAdd(&out[g * 512 + 2 * c2 + 1], a1);
}

extern "C" void kernel_launch(void* const* d_in, const int* in_sizes, int n_in,
                              void* d_out, int out_size, void* d_ws, size_t ws_size,
                              hipStream_t stream) {
    const float* x       = (const float*)d_in[0];
    const int*   batch   = (const int*)d_in[1];
    const float* ga_g_w1 = (const float*)d_in[2];
    const float* ga_g_b1 = (const float*)d_in[3];
    const float* ga_g_w2 = (const float*)d_in[4];
    const float* ga_g_b2 = (const float*)d_in[5];
    const float* ga_n_w  = (const float*)d_in[6];
    const float* ga_n_b  = (const float*)d_in[7];
    const float* g_w1    = (const float*)d_in[8];
    const float* g_b1    = (const float*)d_in[9];
    const float* g_w2    = (const float*)d_in[10];
    const float* g_b2    = (const float*)d_in[11];

    float* out_emb = (float*)d_out;                  // (512, 512)
    float* out_att = out_emb + GG * HH;              // (100000,)

    char* p = (char*)d_ws;
    size_t off = 0;
    auto alloc = [&](size_t bytes) -> char* {
        char* q = p + off;
        off += (bytes + 255) & ~(size_t)255;
        return q;
    };
    u16*   xt    = (u16*)  alloc((size_t)NN * HH * 2);      // relu(x@ga_n_w+b) bf16
    u16*   WT    = (u16*)  alloc((size_t)NPACK * 512 * 2);  // packed W^T bf16
    float* bias  = (float*)alloc(NPACK * 4);
    float* wvec  = (float*)alloc(NPACK * 4);
    float* gs    = (float*)alloc((size_t)NN * 4);
    float* as_   = (float*)alloc((size_t)NN * 4);
    float* gate  = (float*)alloc((size_t)NN * 4);
    int*   starts= (int*)  alloc((GG + 1) * 4);

    k_prep<<<2560, 256, 0, stream>>>(ga_g_w1, ga_g_b1, ga_g_w2, ga_n_w, ga_n_b,
                                     g_w1, g_b1, g_w2, batch, WT, bias, wvec, out_emb, starts);
    k_gemm<<<(NN + 63) / 64, 256, 0, stream>>>(x, WT, bias, wvec, ga_g_b2, g_b2, xt, gs, as_);
    k_seg<<<GG, 256, 0, stream>>>(gs, as_, starts, gate, out_att);
    k_emb<<<dim3(4, GG), 256, 0, stream>>>(xt, gate, starts, out_emb);
}

// Round 5
// 624.582 us; speedup vs baseline: 1.4822x; 1.3033x over previous
//
#include <hip/hip_runtime.h>

#define NN 100000
#define HH 512
#define GG 512
#define NPACK 1280

typedef unsigned short u16;
typedef __bf16 bf16x8 __attribute__((ext_vector_type(8)));
typedef unsigned short u16x8 __attribute__((ext_vector_type(8)));
typedef float f32x16 __attribute__((ext_vector_type(16)));
typedef __attribute__((address_space(1))) void gvoid_t;
typedef __attribute__((address_space(3))) void lvoid_t;

__device__ __forceinline__ u16 f2bf(float f) {
    unsigned u = __float_as_uint(f);
    unsigned r = u + 0x7FFFu + ((u >> 16) & 1u);   // RNE
    return (u16)(r >> 16);
}
__device__ __forceinline__ float bf2f(u16 b) {
    return __uint_as_float(((unsigned)b) << 16);
}

// ---- prep: pack W^T bf16, bias, wvec; convert x->bf16; init scores/out; seg bounds ----
// packed col n: [0,256) = ga_g_w1 ; [256,768) = ga_n_w ; [768,1280) = g_w1
__global__ void k_prep(const float* __restrict__ x,
                       const float* __restrict__ gw1, const float* __restrict__ gb1,
                       const float* __restrict__ gw2v, const float* __restrict__ gb2,
                       const float* __restrict__ nw, const float* __restrict__ nb,
                       const float* __restrict__ aw1, const float* __restrict__ ab1,
                       const float* __restrict__ aw2, const float* __restrict__ ab2,
                       const int* __restrict__ batch,
                       u16* __restrict__ xb, u16* __restrict__ WT,
                       float* __restrict__ bias, float* __restrict__ wvec,
                       float* __restrict__ gs, float* __restrict__ as_,
                       float* __restrict__ out_emb, int* __restrict__ starts) {
    int idx = blockIdx.x * blockDim.x + threadIdx.x;
    int stride = gridDim.x * blockDim.x;
    // x fp32 -> bf16 (vectorized)
    for (int i = idx; i < NN * HH / 4; i += stride) {
        float4 v = reinterpret_cast<const float4*>(x)[i];
        ushort4 o;
        o.x = f2bf(v.x); o.y = f2bf(v.y); o.z = f2bf(v.z); o.w = f2bf(v.w);
        reinterpret_cast<ushort4*>(xb)[i] = o;
    }
    for (int i = idx; i < NPACK * 512; i += stride) {
        int n = i >> 9, k = i & 511;
        float v;
        if (n < 256)      v = gw1[k * 256 + n];
        else if (n < 768) v = nw[k * 512 + (n - 256)];
        else              v = aw1[k * 512 + (n - 768)];
        WT[n * 512 + k] = f2bf(v);   // row n contiguous in k
    }
    for (int n = idx; n < NPACK; n += stride) {
        float bi, wv;
        if (n < 256)      { bi = gb1[n];       wv = gw2v[n]; }
        else if (n < 768) { bi = nb[n - 256];  wv = 0.f; }
        else {
            bi = ab1[n - 768];
            float s = 0.f;
            for (int h = 0; h < 8; ++h) s += aw2[(n - 768) * 8 + h];
            wv = s * 0.125f;
        }
        bias[n] = bi; wvec[n] = wv;
    }
    // seed scores with the layer-2 bias terms (k_gemm atomicAdds partials on top)
    float b2 = gb2[0];
    float bb = 0.f;
    for (int h = 0; h < 8; ++h) bb += ab2[h];
    bb *= 0.125f;
    for (int i = idx; i < NN; i += stride) { gs[i] = b2; as_[i] = bb; }
    for (int i = idx; i < GG * HH; i += stride) out_emb[i] = 0.f;
    for (int g = idx; g <= GG; g += stride) {
        if (g == GG) { starts[GG] = NN; continue; }
        int lo = 0, hi = NN;
        while (lo < hi) { int mid = (lo + hi) >> 1; if (batch[mid] < g) lo = mid + 1; else hi = mid; }
        starts[g] = lo;
    }
}

// ---- fused GEMM: tile 256x128, K-chunk 64 via glds, 32x32x16 MFMA, wave tile 64x128 ----
// grid (10 nt, 391 mt), x-major so the 10 blocks sharing an A panel co-dispatch (L2/L3 reuse).
// LDS A chunk layout [kt 0..3][rg 0..7]: 1KB segment, entry lane*16 = A[m0+rg*32+(lane&31)]
//   [k = kc*64 + kt*16 + (lane>>5)*8 ..+8) — frag reads are base+lane*16, conflict-free.
// nt 0-1: gate-score atomics | nt 2-5: xt store | nt 6-9: att-score atomics.
__global__ __launch_bounds__(256, 2)
void k_gemm(const u16* __restrict__ A, const u16* __restrict__ B,
            const float* __restrict__ bias, const float* __restrict__ wvec,
            u16* __restrict__ xt, float* __restrict__ gs, float* __restrict__ as_) {
    __shared__ __align__(16) char ldsA[32768];   // 256 rows x 64 k bf16
    __shared__ __align__(16) char ldsB[16384];   // 128 cols x 64 k bf16

    const int tid = threadIdx.x;
    const int lane = tid & 63;
    const int w = tid >> 6;                      // wave w -> rows [w*64, w*64+64)
    const int nt = blockIdx.x;
    const int m0 = blockIdx.y * 256;
    const int n0 = nt * 128;
    const int r32 = lane & 31, khl = lane >> 5;

    // staging pointers (u16 units); each wave stages its own two A rgroups + one B rgroup
    int rowA0 = m0 + (2 * w) * 32 + r32;     if (rowA0 >= NN) rowA0 = NN - 1;
    int rowA1 = m0 + (2 * w + 1) * 32 + r32; if (rowA1 >= NN) rowA1 = NN - 1;
    const u16* gA0 = A + (size_t)rowA0 * 512 + khl * 8;
    const u16* gA1 = A + (size_t)rowA1 * 512 + khl * 8;
    const u16* gB  = B + (size_t)(n0 + w * 32 + r32) * 512 + khl * 8;

    f32x16 acc[2][4];
#pragma unroll
    for (int i = 0; i < 2; ++i)
#pragma unroll
        for (int j = 0; j < 4; ++j) acc[i][j] = {0.f};

    for (int kc = 0; kc < 8; ++kc) {
#pragma unroll
        for (int kt = 0; kt < 4; ++kt) {
            __builtin_amdgcn_global_load_lds((gvoid_t*)(gA0 + kt * 16),
                (lvoid_t*)(ldsA + kt * 8192 + (2 * w) * 1024 + lane * 16), 16, 0, 0);
            __builtin_amdgcn_global_load_lds((gvoid_t*)(gA1 + kt * 16),
                (lvoid_t*)(ldsA + kt * 8192 + (2 * w + 1) * 1024 + lane * 16), 16, 0, 0);
            __builtin_amdgcn_global_load_lds((gvoid_t*)(gB + kt * 16),
                (lvoid_t*)(ldsB + kt * 4096 + w * 1024 + lane * 16), 16, 0, 0);
        }
        __syncthreads();
#pragma unroll
        for (int kt = 0; kt < 4; ++kt) {
            bf16x8 a0 = *(const bf16x8*)(ldsA + kt * 8192 + (2 * w) * 1024 + lane * 16);
            bf16x8 a1 = *(const bf16x8*)(ldsA + kt * 8192 + (2 * w + 1) * 1024 + lane * 16);
            bf16x8 b0 = *(const bf16x8*)(ldsB + kt * 4096 + 0 * 1024 + lane * 16);
            bf16x8 b1 = *(const bf16x8*)(ldsB + kt * 4096 + 1 * 1024 + lane * 16);
            bf16x8 b2v = *(const bf16x8*)(ldsB + kt * 4096 + 2 * 1024 + lane * 16);
            bf16x8 b3 = *(const bf16x8*)(ldsB + kt * 4096 + 3 * 1024 + lane * 16);
            acc[0][0] = __builtin_amdgcn_mfma_f32_32x32x16_bf16(a0, b0, acc[0][0], 0, 0, 0);
            acc[0][1] = __builtin_amdgcn_mfma_f32_32x32x16_bf16(a0, b1, acc[0][1], 0, 0, 0);
            acc[0][2] = __builtin_amdgcn_mfma_f32_32x32x16_bf16(a0, b2v, acc[0][2], 0, 0, 0);
            acc[0][3] = __builtin_amdgcn_mfma_f32_32x32x16_bf16(a0, b3, acc[0][3], 0, 0, 0);
            acc[1][0] = __builtin_amdgcn_mfma_f32_32x32x16_bf16(a1, b0, acc[1][0], 0, 0, 0);
            acc[1][1] = __builtin_amdgcn_mfma_f32_32x32x16_bf16(a1, b1, acc[1][1], 0, 0, 0);
            acc[1][2] = __builtin_amdgcn_mfma_f32_32x32x16_bf16(a1, b2v, acc[1][2], 0, 0, 0);
            acc[1][3] = __builtin_amdgcn_mfma_f32_32x32x16_bf16(a1, b3, acc[1][3], 0, 0, 0);
        }
        __syncthreads();
        gA0 += 64; gA1 += 64; gB += 64;          // advance 128 B (64 u16) per chunk
    }

    // ---- epilogue. C/D 32x32: col = lane&31, row = (reg&3)+8*(reg>>2)+4*(lane>>5) [m74/m101]
    const int colbase = n0 + r32;
    float bv[4];
#pragma unroll
    for (int nf = 0; nf < 4; ++nf) bv[nf] = bias[colbase + nf * 32];

    if (nt >= 2 && nt < 6) {
#pragma unroll
        for (int mf = 0; mf < 2; ++mf) {
#pragma unroll
            for (int reg = 0; reg < 16; ++reg) {
                int row = m0 + w * 64 + mf * 32 + (reg & 3) + 8 * (reg >> 2) + 4 * khl;
                if (row < NN) {
#pragma unroll
                    for (int nf = 0; nf < 4; ++nf) {
                        float v = fmaxf(acc[mf][nf][reg] + bv[nf], 0.f);
                        xt[(size_t)row * 512 + (colbase + nf * 32 - 256)] = f2bf(v);
                    }
                }
            }
        }
    } else {
        float* tgt = (nt < 2) ? gs : as_;
        float wv[4];
#pragma unroll
        for (int nf = 0; nf < 4; ++nf) wv[nf] = wvec[colbase + nf * 32];
#pragma unroll
        for (int mf = 0; mf < 2; ++mf) {
#pragma unroll
            for (int reg = 0; reg < 16; ++reg) {
                float p = 0.f;
#pragma unroll
                for (int nf = 0; nf < 4; ++nf)
                    p += fmaxf(acc[mf][nf][reg] + bv[nf], 0.f) * wv[nf];
                p += __shfl_xor(p, 1); p += __shfl_xor(p, 2);
                p += __shfl_xor(p, 4); p += __shfl_xor(p, 8); p += __shfl_xor(p, 16);
                int row = m0 + w * 64 + mf * 32 + (reg & 3) + 8 * (reg >> 2) + 4 * khl;
                if (r32 == 0 && row < NN) atomicAdd(tgt + row, p);
            }
        }
    }
}

// ------- per-graph softmax: max + denom + normalize, one block per graph -------
__global__ void k_seg(const float* __restrict__ gs, const float* __restrict__ as_,
                      const int* __restrict__ starts,
                      float* __restrict__ gate, float* __restrict__ attn) {
    int g = blockIdx.x;
    int s0 = starts[g], s1 = starts[g + 1];
    int tid = threadIdx.x, lane = tid & 63, w = tid >> 6;
    __shared__ float red[8];
    float lmg = -3.0e38f, lma = -3.0e38f;
    for (int i = s0 + tid; i < s1; i += 256) {
        lmg = fmaxf(lmg, gs[i]); lma = fmaxf(lma, as_[i]);
    }
    for (int o = 32; o; o >>= 1) {
        lmg = fmaxf(lmg, __shfl_xor(lmg, o));
        lma = fmaxf(lma, __shfl_xor(lma, o));
    }
    if (lane == 0) { red[w] = lmg; red[4 + w] = lma; }
    __syncthreads();
    float Mg = fmaxf(fmaxf(red[0], red[1]), fmaxf(red[2], red[3]));
    float Ma = fmaxf(fmaxf(red[4], red[5]), fmaxf(red[6], red[7]));
    __syncthreads();
    float sgv = 0.f, sav = 0.f;
    for (int i = s0 + tid; i < s1; i += 256) {
        sgv += expf(gs[i] - Mg); sav += expf(as_[i] - Ma);
    }
    for (int o = 32; o; o >>= 1) { sgv += __shfl_xor(sgv, o); sav += __shfl_xor(sav, o); }
    if (lane == 0) { red[w] = sgv; red[4 + w] = sav; }
    __syncthreads();
    float invg = 1.f / (red[0] + red[1] + red[2] + red[3] + 1e-16f);
    float inva = 1.f / (red[4] + red[5] + red[6] + red[7] + 1e-16f);
    for (int i = s0 + tid; i < s1; i += 256) {
        gate[i] = expf(gs[i] - Mg) * invg;
        attn[i] = expf(as_[i] - Ma) * inva;
    }
}

// ---------------- graph embedding: segment-weighted sum of xt ----------------
__global__ void k_emb(const u16* __restrict__ xt, const float* __restrict__ gate,
                      const int* __restrict__ starts, float* __restrict__ out) {
    int g = blockIdx.y;
    int part = blockIdx.x;
    int s0 = starts[g], s1 = starts[g + 1];
    int len = s1 - s0;
    int p0 = s0 + (len * part) / 4, p1 = s0 + (len * (part + 1)) / 4;
    int c2 = threadIdx.x;
    float a0 = 0.f, a1 = 0.f;
    for (int n = p0; n < p1; ++n) {
        float gn = gate[n];
        ushort2 u = reinterpret_cast<const ushort2*>(xt + (size_t)n * 512)[c2];
        a0 += gn * bf2f(u.x);
        a1 += gn * bf2f(u.y);
    }
    atomicAdd(&out[g * 512 + 2 * c2], a0);
    atomicAdd(&out[g * 512 + 2 * c2 + 1], a1);
}

extern "C" void kernel_launch(void* const* d_in, const int* in_sizes, int n_in,
                              void* d_out, int out_size, void* d_ws, size_t ws_size,
                              hipStream_t stream) {
    const float* x       = (const float*)d_in[0];
    const int*   batch   = (const int*)d_in[1];
    const float* ga_g_w1 = (const float*)d_in[2];
    const float* ga_g_b1 = (const float*)d_in[3];
    const float* ga_g_w2 = (const float*)d_in[4];
    const float* ga_g_b2 = (const float*)d_in[5];
    const float* ga_n_w  = (const float*)d_in[6];
    const float* ga_n_b  = (const float*)d_in[7];
    const float* g_w1    = (const float*)d_in[8];
    const float* g_b1    = (const float*)d_in[9];
    const float* g_w2    = (const float*)d_in[10];
    const float* g_b2    = (const float*)d_in[11];

    float* out_emb = (float*)d_out;                  // (512, 512)
    float* out_att = out_emb + GG * HH;              // (100000,)

    char* p = (char*)d_ws;
    size_t off = 0;
    auto alloc = [&](size_t bytes) -> char* {
        char* q = p + off;
        off += (bytes + 255) & ~(size_t)255;
        return q;
    };
    u16*   xb    = (u16*)  alloc((size_t)NN * HH * 2);      // x bf16
    u16*   xt    = (u16*)  alloc((size_t)NN * HH * 2);      // relu(x@ga_n_w+b) bf16
    u16*   WT    = (u16*)  alloc((size_t)NPACK * 512 * 2);  // packed W^T bf16
    float* bias  = (float*)alloc(NPACK * 4);
    float* wvec  = (float*)alloc(NPACK * 4);
    float* gs    = (float*)alloc((size_t)NN * 4);
    float* as_   = (float*)alloc((size_t)NN * 4);
    float* gate  = (float*)alloc((size_t)NN * 4);
    int*   starts= (int*)  alloc((GG + 1) * 4);

    k_prep<<<4096, 256, 0, stream>>>(x, ga_g_w1, ga_g_b1, ga_g_w2, ga_g_b2,
                                     ga_n_w, ga_n_b, g_w1, g_b1, g_w2, g_b2,
                                     batch, xb, WT, bias, wvec, gs, as_, out_emb, starts);
    k_gemm<<<dim3(10, (NN + 255) / 256), 256, 0, stream>>>(xb, WT, bias, wvec, xt, gs, as_);
    k_seg<<<GG, 256, 0, stream>>>(gs, as_, starts, gate, out_att);
    k_emb<<<dim3(4, GG), 256, 0, stream>>>(xt, gate, starts, out_emb);
}